// Round 1
// baseline (262.677 us; speedup 1.0000x reference)
//
#include <hip/hip_runtime.h>

// Problem constants (from reference)
#define BQ_B   8
#define BQ_N   4096
#define NS     32
#define C1     32
#define C2     64
#define R2     0.0625f
#define R2_LO  (0.0625f - 1e-5f)
#define R2_HI  (0.0625f + 1e-5f)

#define PTS    64            // points per block (one per lane)
#define NW     4             // waves per block = scan chunks
#define CHUNK  (BQ_N / NW)   // 1024 m's per wave

// LDS budget (static, must stay < 64KB):
//  lists 32KB + counts 1KB + queue 8KB + pooled 16KB + ctr/dens/misc ~1KB = ~59.4KB
__global__ __launch_bounds__(256, 1) void lse_kernel(
    const float* __restrict__ xyz,
    const float* __restrict__ w1, const float* __restrict__ b1,
    const float* __restrict__ w2, const float* __restrict__ b2,
    float* __restrict__ out)
{
    __shared__ int      lists[NW][PTS][NS];   // per-(chunk,point) ordered valid idx
    __shared__ int      counts[NW][PTS];      // uncapped valid count per chunk
    __shared__ int      queue[PTS * NS];      // compacted (point,idx) sample queue
    __shared__ unsigned pooled[PTS][C2];      // max-pool accum (float bits, >=0)
    __shared__ float    ctr[PTS][3];
    __shared__ float    dens[PTS];
    __shared__ int      qtotal;

    const int tid  = threadIdx.x;
    const int lane = tid & 63;
    const int wf   = tid >> 6;
    const int pt0  = blockIdx.x * PTS;     // flat point base (never straddles a batch)
    const int b    = pt0 / BQ_N;
    const int bbase = b * BQ_N;

    // init pooled accumulators to 0 (ReLU outputs are >= 0)
    for (int u = tid; u < PTS * C2; u += 256) ((unsigned*)pooled)[u] = 0u;

    // each lane's center point (per-wave duplicate load, cache-hot)
    const float cx = xyz[(size_t)(pt0 + lane) * 3 + 0];
    const float cy = xyz[(size_t)(pt0 + lane) * 3 + 1];
    const float cz = xyz[(size_t)(pt0 + lane) * 3 + 2];
    if (tid < PTS) { ctr[tid][0] = cx; ctr[tid][1] = cy; ctr[tid][2] = cz; }

    // ---------------- Phase 1: ball-query scan ----------------
    // wave wf scans m in [wf*CHUNK, (wf+1)*CHUNK) for all 64 points (lane=point).
    // m is wave-uniform -> readfirstlane forces scalar loads (s_load via sL1/L2).
    int cnt = 0;
    const float* xb = xyz + (size_t)(bbase + wf * CHUNK) * 3;
    int* mylist = lists[wf][lane];
    #pragma unroll 4
    for (int i = 0; i < CHUNK; ++i) {
        const int iu = __builtin_amdgcn_readfirstlane(i);
        const float qx = xb[iu * 3 + 0];
        const float qy = xb[iu * 3 + 1];
        const float qz = xb[iu * 3 + 2];
        const float dx = qx - cx, dy = qy - cy, dz = qz - cz;
        const float d2 = fmaf(dz, dz, fmaf(dy, dy, dx * dx));
        if (d2 < R2_HI) {                      // rare (~0.15% of pairs)
            bool valid = d2 < R2_LO;
            if (!valid) {                      // borderline: decide in fp64 (exact)
                const double ddx = (double)qx - (double)cx;
                const double ddy = (double)qy - (double)cy;
                const double ddz = (double)qz - (double)cz;
                valid = (ddx * ddx + ddy * ddy + ddz * ddz) < 0.0625;
            }
            if (valid) {
                if (cnt < NS) mylist[cnt] = wf * CHUNK + i;  // batch-local index
                cnt++;
            }
        }
    }
    counts[wf][lane] = cnt;
    __syncthreads();

    // ---------------- Phase 2: merge first-32 in index order (wave 0) ----------------
    if (tid < PTS) {
        const int p = tid;
        int ktot = counts[0][p] + counts[1][p] + counts[2][p] + counts[3][p];
        const int k = ktot < NS ? ktot : NS;   // == unique_cnt (self always valid -> k>=1)
        dens[p] = (float)k * (1.0f / (float)C2);

        // exclusive prefix of k across the 64 points (single wave, shfl scan)
        int incl = k;
        #pragma unroll
        for (int d = 1; d < 64; d <<= 1) {
            int v = __shfl_up(incl, d, 64);
            if (lane >= d) incl += v;
        }
        const int excl = incl - k;
        if (p == PTS - 1) qtotal = incl;

        // emit first k indices (chunks are in ascending-m order; lists are ordered)
        int pos = 0;
        for (int c = 0; c < NW; ++c) {
            int cc = counts[c][p]; if (cc > NS) cc = NS;
            for (int j = 0; j < cc && pos < k; ++j) {
                queue[excl + pos] = (p << 12) | lists[c][p][j];
                pos++;
            }
        }
    }
    __syncthreads();

    // ---------------- Phase 3: MLP on distinct samples only ----------------
    const int Q = qtotal;
    for (int j = tid; j < Q; j += 256) {
        const int e   = queue[j];
        const int p   = e >> 12;
        const int idx = e & (BQ_N - 1);
        const float* nb = xyz + (size_t)(bbase + idx) * 3;
        const float rx = nb[0] - ctr[p][0];
        const float ry = nb[1] - ctr[p][1];
        const float rz = nb[2] - ctr[p][2];

        float h1[C1];
        #pragma unroll
        for (int c = 0; c < C1; ++c) {   // w1/b1 uniform-indexed -> scalar loads
            float a = fmaf(w1[c * 3 + 2], rz,
                      fmaf(w1[c * 3 + 1], ry,
                      fmaf(w1[c * 3 + 0], rx, b1[c])));
            h1[c] = a > 0.0f ? a : 0.0f;
        }
        #pragma unroll 2
        for (int o = 0; o < C2; ++o) {   // w2 uniform-indexed -> scalar loads
            float acc = b2[o];
            #pragma unroll
            for (int i = 0; i < C1; ++i) acc = fmaf(w2[o * C1 + i], h1[i], acc);
            acc = acc > 0.0f ? acc : 0.0f;
            atomicMax(&pooled[p][o], __float_as_uint(acc));  // float>=0: bit-monotone
        }
    }
    __syncthreads();

    // ---------------- Phase 4: write out (B, N, 65) ----------------
    for (int u = tid; u < PTS * (C2 + 1); u += 256) {
        const int p = u / (C2 + 1);
        const int c = u % (C2 + 1);
        const float v = (c < C2) ? __uint_as_float(pooled[p][c]) : dens[p];
        out[(size_t)(pt0 + p) * (C2 + 1) + c] = v;
    }
}

extern "C" void kernel_launch(void* const* d_in, const int* in_sizes, int n_in,
                              void* d_out, int out_size, void* d_ws, size_t ws_size,
                              hipStream_t stream) {
    const float* xyz = (const float*)d_in[0];
    const float* w1  = (const float*)d_in[1];
    const float* b1  = (const float*)d_in[2];
    const float* w2  = (const float*)d_in[3];
    const float* b2  = (const float*)d_in[4];
    float* out = (float*)d_out;

    const int nblocks = (BQ_B * BQ_N) / PTS;  // 512
    lse_kernel<<<nblocks, 256, 0, stream>>>(xyz, w1, b1, w2, b2, out);
}

// Round 2
// 157.559 us; speedup vs baseline: 1.6672x; 1.6672x over previous
//
#include <hip/hip_runtime.h>

// Problem constants (from reference)
#define BQ_B   8
#define BQ_N   4096
#define NS     32
#define C1     32
#define C2     64
#define R2_LO  (0.0625f - 1e-5f)
#define R2_HI  (0.0625f + 1e-5f)

#define PBLK   32            // centers per block
#define CPW    8             // centers per wave (4 waves * 8 = 32)

// LDS ~17KB -> LDS allows 9 blocks/CU; launch_bounds(256,4) -> 4 blocks/CU,
// grid 1024 = 4/CU exactly resident.
__global__ __launch_bounds__(256, 4) void lse_kernel(
    const float* __restrict__ xyz,
    const float* __restrict__ w1, const float* __restrict__ b1,
    const float* __restrict__ w2, const float* __restrict__ b2,
    float* __restrict__ out)
{
    __shared__ int      lists[PBLK][NS];     // first-32 valid idx per center, ascending
    __shared__ int      counts[PBLK];        // uncapped valid count
    __shared__ int      queue[PBLK * NS];    // compacted (p<<12 | idx)
    __shared__ unsigned pooled[PBLK][C2];    // max-pool accum (float bits, >=0)
    __shared__ float    ctr[PBLK][3];
    __shared__ float    dens[PBLK];
    __shared__ int      qtotal;

    const int tid   = threadIdx.x;
    const int lane  = tid & 63;
    const int wf    = tid >> 6;
    const int pt0   = blockIdx.x * PBLK;     // flat point base (never straddles batch)
    const int b     = pt0 >> 12;             // / 4096
    const int bbase = b << 12;

    // init pooled accumulators (ReLU outputs >= 0)
    for (int u = tid; u < PBLK * C2; u += 256) ((unsigned*)pooled)[u] = 0u;
    if (tid < PBLK) {
        ctr[tid][0] = xyz[(size_t)(pt0 + tid) * 3 + 0];
        ctr[tid][1] = xyz[(size_t)(pt0 + tid) * 3 + 1];
        ctr[tid][2] = xyz[(size_t)(pt0 + tid) * 3 + 2];
    }

    // ---- Phase 1: ball-query scan. lane = candidate m, centers wave-uniform ----
    const int c0 = pt0 + wf * CPW;           // this wave's first center (global)
    float ccx[CPW], ccy[CPW], ccz[CPW];
    #pragma unroll
    for (int j = 0; j < CPW; ++j) {          // uniform addresses -> scalar loads
        const int g = __builtin_amdgcn_readfirstlane(c0 + j);
        ccx[j] = xyz[(size_t)g * 3 + 0];
        ccy[j] = xyz[(size_t)g * 3 + 1];
        ccz[j] = xyz[(size_t)g * 3 + 2];
    }
    int cnt[CPW];
    #pragma unroll
    for (int j = 0; j < CPW; ++j) cnt[j] = 0;

    for (int m0 = 0; m0 < BQ_N; m0 += 64) {
        const int m = m0 + lane;
        const float* q = xyz + (size_t)(bbase + m) * 3;
        const float qx = q[0], qy = q[1], qz = q[2];   // coalesced, L1/L2-hot
        #pragma unroll
        for (int j = 0; j < CPW; ++j) {
            const float dx = qx - ccx[j], dy = qy - ccy[j], dz = qz - ccz[j];
            const float d2 = fmaf(dz, dz, fmaf(dy, dy, dx * dx));
            const bool near = d2 < R2_HI;
            const unsigned long long mN = __ballot(near);
            if (mN == 0ull) continue;                   // ~91% of tile-center checks
            const bool strict = d2 < R2_LO;
            unsigned long long mask = __ballot(strict);
            if (mask != mN) {                           // borderline: exact fp64
                bool valid = strict;
                if (near && !strict) {
                    const double ddx = (double)qx - (double)ccx[j];
                    const double ddy = (double)qy - (double)ccy[j];
                    const double ddz = (double)qz - (double)ccz[j];
                    valid = (ddx * ddx + ddy * ddy + ddz * ddz) < 0.0625;
                }
                mask = __ballot(valid);
            }
            const unsigned mlo = (unsigned)mask, mhi = (unsigned)(mask >> 32);
            const int rank = __builtin_amdgcn_mbcnt_hi(
                                 mhi, __builtin_amdgcn_mbcnt_lo(mlo, 0));
            const bool valid = (mask >> lane) & 1ull;
            const int pos = cnt[j] + rank;
            if (valid && pos < NS) lists[wf * CPW + j][pos] = m;  // ascending order
            cnt[j] += __popcll(mask);
        }
    }
    if (lane == 0) {
        #pragma unroll
        for (int j = 0; j < CPW; ++j) counts[wf * CPW + j] = cnt[j];
    }
    __syncthreads();

    // ---- Phase 2: density + compact sample queue (first wave, 32 threads) ----
    if (tid < PBLK) {
        const int p = tid;
        int ktot = counts[p];
        const int k = ktot < NS ? ktot : NS;   // == unique_cnt (self valid -> k>=1)
        dens[p] = (float)k * (1.0f / (float)C2);

        int incl = k;                          // exclusive prefix over 32 lanes
        #pragma unroll
        for (int d = 1; d < PBLK; d <<= 1) {
            int v = __shfl_up(incl, d, 64);
            if (lane >= d) incl += v;
        }
        const int excl = incl - k;
        if (p == PBLK - 1) qtotal = incl;

        for (int j = 0; j < k; ++j)
            queue[excl + j] = (p << 12) | lists[p][j];
    }
    __syncthreads();

    // ---- Phase 3: MLP on distinct samples only ----
    const int Q = qtotal;
    for (int j = tid; j < Q; j += 256) {
        const int e   = queue[j];
        const int p   = e >> 12;
        const int idx = e & (BQ_N - 1);
        const float* nb = xyz + (size_t)(bbase + idx) * 3;
        const float rx = nb[0] - ctr[p][0];
        const float ry = nb[1] - ctr[p][1];
        const float rz = nb[2] - ctr[p][2];

        float h1[C1];
        #pragma unroll
        for (int c = 0; c < C1; ++c) {          // w1/b1 uniform -> scalar loads
            float a = fmaf(w1[c * 3 + 2], rz,
                      fmaf(w1[c * 3 + 1], ry,
                      fmaf(w1[c * 3 + 0], rx, b1[c])));
            h1[c] = a > 0.0f ? a : 0.0f;
        }
        #pragma unroll 2
        for (int o = 0; o < C2; ++o) {          // w2 uniform -> scalar loads
            float acc = b2[o];
            #pragma unroll
            for (int i = 0; i < C1; ++i) acc = fmaf(w2[o * C1 + i], h1[i], acc);
            acc = acc > 0.0f ? acc : 0.0f;
            atomicMax(&pooled[p][o], __float_as_uint(acc));
        }
    }
    __syncthreads();

    // ---- Phase 4: write out (B, N, 65) ----
    for (int u = tid; u < PBLK * (C2 + 1); u += 256) {
        const int p = u / (C2 + 1);
        const int c = u % (C2 + 1);
        const float v = (c < C2) ? __uint_as_float(pooled[p][c]) : dens[p];
        out[(size_t)(pt0 + p) * (C2 + 1) + c] = v;
    }
}

extern "C" void kernel_launch(void* const* d_in, const int* in_sizes, int n_in,
                              void* d_out, int out_size, void* d_ws, size_t ws_size,
                              hipStream_t stream) {
    const float* xyz = (const float*)d_in[0];
    const float* w1  = (const float*)d_in[1];
    const float* b1  = (const float*)d_in[2];
    const float* w2  = (const float*)d_in[3];
    const float* b2  = (const float*)d_in[4];
    float* out = (float*)d_out;

    const int nblocks = (BQ_B * BQ_N) / PBLK;  // 1024
    lse_kernel<<<nblocks, 256, 0, stream>>>(xyz, w1, b1, w2, b2, out);
}

// Round 3
// 149.817 us; speedup vs baseline: 1.7533x; 1.0517x over previous
//
#include <hip/hip_runtime.h>

// Problem constants (from reference)
#define BQ_B   8
#define BQ_N   4096
#define NS     32
#define C1     32
#define C2     64
#define R2C    0.0625f
#define BAND   2e-4f          // fp32 cancellation band for the expanded-form test

#define PBLK   32             // centers per block
#define CPW    8              // centers per wave (4 waves * 8 = 32)

// LDS ~17KB. grid 1024 = 4 blocks/CU resident (16 waves/CU).
__global__ __launch_bounds__(256, 4) void lse_kernel(
    const float* __restrict__ xyz,
    const float* __restrict__ w1, const float* __restrict__ b1,
    const float* __restrict__ w2, const float* __restrict__ b2,
    float* __restrict__ out)
{
    __shared__ int      lists[PBLK][NS];      // first-32 valid idx per center, ascending
    __shared__ int      counts[PBLK];         // uncapped valid count
    __shared__ int      queue[PBLK * NS];     // compacted (p<<12 | idx)
    __shared__ unsigned pooled[PBLK][C2 + 1]; // stride 65: bank=(p+o)%32, no wave-wide conflict
    __shared__ float    ctr[PBLK][3];
    __shared__ float    dens[PBLK];
    __shared__ int      qtotal;

    const int tid   = threadIdx.x;
    const int lane  = tid & 63;
    const int wf    = tid >> 6;
    const int pt0   = blockIdx.x * PBLK;      // never straddles a batch
    const int b     = pt0 >> 12;
    const int bbase = b << 12;

    for (int u = tid; u < PBLK * (C2 + 1); u += 256) ((unsigned*)pooled)[u] = 0u;
    if (tid < PBLK) {
        ctr[tid][0] = xyz[(size_t)(pt0 + tid) * 3 + 0];
        ctr[tid][1] = xyz[(size_t)(pt0 + tid) * 3 + 1];
        ctr[tid][2] = xyz[(size_t)(pt0 + tid) * 3 + 2];
    }

    // ---- per-wave center constants: t = q·(-2c) + (|c|^2 - r^2 - band) ----
    const int c0 = pt0 + wf * CPW;
    float c2x[CPW], c2y[CPW], c2z[CPW], scc[CPW];
    #pragma unroll
    for (int j = 0; j < CPW; ++j) {           // uniform addr -> scalar loads
        const int g = __builtin_amdgcn_readfirstlane(c0 + j);
        const float cx = xyz[(size_t)g * 3 + 0];
        const float cy = xyz[(size_t)g * 3 + 1];
        const float cz = xyz[(size_t)g * 3 + 2];
        c2x[j] = -2.0f * cx;                  // exact (pow2 scale)
        c2y[j] = -2.0f * cy;
        c2z[j] = -2.0f * cz;
        scc[j] = fmaf(cx, cx, fmaf(cy, cy, cz * cz)) - (R2C + BAND);
    }
    int cnt[CPW];
    #pragma unroll
    for (int j = 0; j < CPW; ++j) cnt[j] = 0;

    // ---- Phase 1: scan, lane = candidate, software-pipelined tile load ----
    const float* xb = xyz + (size_t)bbase * 3;
    float qx = xb[lane * 3 + 0];
    float qy = xb[lane * 3 + 1];
    float qz = xb[lane * 3 + 2];

    for (int m0 = 0; m0 < BQ_N; m0 += 64) {
        float nqx = 0.f, nqy = 0.f, nqz = 0.f;
        if (m0 + 64 < BQ_N) {                 // prefetch next tile (uniform branch)
            const int mn = m0 + 64 + lane;
            nqx = xb[mn * 3 + 0];
            nqy = xb[mn * 3 + 1];
            nqz = xb[mn * 3 + 2];
        }
        const float nsq = -fmaf(qx, qx, fmaf(qy, qy, qz * qz));  // -|q|^2

        #pragma unroll
        for (int j = 0; j < CPW; ++j) {
            const float t = fmaf(qx, c2x[j], fmaf(qy, c2y[j], fmaf(qz, c2z[j], scc[j])));
            unsigned long long mask = __ballot(t < nsq);         // near: d2 < r2+band
            if (mask == 0ull) continue;                          // ~91% of checks

            const float u = t - nsq;                             // = d2 - r2 - band
            const bool nearb  = (mask >> lane) & 1ull;
            const bool strict = u < (-2.0f * BAND);              // d2 < r2-band
            bool valid = strict;
            const unsigned long long mS = __ballot(strict);
            if (mS != mask) {                                    // borderline: exact fp64
                if (nearb && !strict) {
                    const double cx = -0.5 * (double)c2x[j];     // exact recovery
                    const double cy = -0.5 * (double)c2y[j];
                    const double cz = -0.5 * (double)c2z[j];
                    const double dx = (double)qx - cx;
                    const double dy = (double)qy - cy;
                    const double dz = (double)qz - cz;
                    valid = (dx * dx + dy * dy + dz * dz) < 0.0625;
                }
                mask = __ballot(valid);
                if (mask == 0ull) continue;
            }
            const unsigned mlo = (unsigned)mask, mhi = (unsigned)(mask >> 32);
            const int rank = __builtin_amdgcn_mbcnt_hi(
                                 mhi, __builtin_amdgcn_mbcnt_lo(mlo, 0));
            const int pos = cnt[j] + rank;
            if (valid && pos < NS) lists[wf * CPW + j][pos] = m0 + lane;
            cnt[j] += __popcll(mask);
        }
        qx = nqx; qy = nqy; qz = nqz;
    }
    if (lane == 0) {
        #pragma unroll
        for (int j = 0; j < CPW; ++j) counts[wf * CPW + j] = cnt[j];
    }
    __syncthreads();

    // ---- Phase 2: density + compact queue (first 32 threads) ----
    if (tid < PBLK) {
        const int p = tid;
        const int ktot = counts[p];
        const int k = ktot < NS ? ktot : NS;   // == unique_cnt
        dens[p] = (float)k * (1.0f / (float)C2);

        int incl = k;
        #pragma unroll
        for (int d = 1; d < PBLK; d <<= 1) {
            int v = __shfl_up(incl, d, 64);
            if (lane >= d) incl += v;
        }
        const int excl = incl - k;
        if (p == PBLK - 1) qtotal = incl;

        for (int j = 0; j < k; ++j)
            queue[excl + j] = (p << 12) | lists[p][j];
    }
    __syncthreads();

    // ---- Phase 3: MLP on distinct samples ----
    const int Q = qtotal;
    for (int j = tid; j < Q; j += 256) {
        const int e   = queue[j];
        const int p   = e >> 12;
        const int idx = e & (BQ_N - 1);
        const float* nb = xyz + (size_t)(bbase + idx) * 3;
        const float rx = nb[0] - ctr[p][0];
        const float ry = nb[1] - ctr[p][1];
        const float rz = nb[2] - ctr[p][2];

        float h1[C1];
        #pragma unroll
        for (int c = 0; c < C1; ++c) {          // w1/b1 uniform -> scalar loads
            float a = fmaf(w1[c * 3 + 2], rz,
                      fmaf(w1[c * 3 + 1], ry,
                      fmaf(w1[c * 3 + 0], rx, b1[c])));
            h1[c] = a > 0.0f ? a : 0.0f;
        }
        #pragma unroll 2
        for (int o = 0; o < C2; ++o) {          // w2 uniform -> scalar loads
            float acc = b2[o];
            #pragma unroll
            for (int i = 0; i < C1; ++i) acc = fmaf(w2[o * C1 + i], h1[i], acc);
            acc = acc > 0.0f ? acc : 0.0f;
            atomicMax(&pooled[p][o], __float_as_uint(acc));
        }
    }
    __syncthreads();

    // ---- Phase 4: write out (B, N, 65) ----
    for (int u = tid; u < PBLK * (C2 + 1); u += 256) {
        const int p = u / (C2 + 1);
        const int c = u % (C2 + 1);
        const float v = (c < C2) ? __uint_as_float(pooled[p][c]) : dens[p];
        out[(size_t)(pt0 + p) * (C2 + 1) + c] = v;
    }
}

extern "C" void kernel_launch(void* const* d_in, const int* in_sizes, int n_in,
                              void* d_out, int out_size, void* d_ws, size_t ws_size,
                              hipStream_t stream) {
    const float* xyz = (const float*)d_in[0];
    const float* w1  = (const float*)d_in[1];
    const float* b1  = (const float*)d_in[2];
    const float* w2  = (const float*)d_in[3];
    const float* b2  = (const float*)d_in[4];
    float* out = (float*)d_out;

    const int nblocks = (BQ_B * BQ_N) / PBLK;  // 1024
    lse_kernel<<<nblocks, 256, 0, stream>>>(xyz, w1, b1, w2, b2, out);
}

// Round 4
// 127.217 us; speedup vs baseline: 2.0648x; 1.1776x over previous
//
#include <hip/hip_runtime.h>

// Problem constants (from reference)
#define BQ_B   8
#define BQ_N   4096
#define NS     32
#define C1     32
#define C2     64
#define R2C    0.0625f
#define BAND   2e-4f          // fp32 cancellation band for the expanded-form test

#define PBLK   16             // centers per block
#define CPW    4              // centers per wave (4 waves * 4 = 16)
#define NPTS   (BQ_B * BQ_N)

// ---- SoA preprocessing: xyz (N,3) -> x[N], y[N], z[N] in workspace ----
__global__ __launch_bounds__(256) void soa_kernel(
    const float* __restrict__ xyz,
    float* __restrict__ sx, float* __restrict__ sy, float* __restrict__ sz)
{
    const int i = blockIdx.x * 256 + threadIdx.x;
    if (i < NPTS) {
        sx[i] = xyz[(size_t)i * 3 + 0];
        sy[i] = xyz[(size_t)i * 3 + 1];
        sz[i] = xyz[(size_t)i * 3 + 2];
    }
}

// LDS ~8.6KB; launch_bounds(256,8) -> 8 blocks/CU; grid 2048 = 8/CU exact.
template <bool SOA>
__global__ __launch_bounds__(256, 8) void lse_kernel(
    const float* __restrict__ xyz,
    const float* __restrict__ sx, const float* __restrict__ sy,
    const float* __restrict__ sz,
    const float* __restrict__ w1, const float* __restrict__ b1,
    const float* __restrict__ w2, const float* __restrict__ b2,
    float* __restrict__ out)
{
    __shared__ int      lists[PBLK][NS];      // first-32 valid idx, ascending
    __shared__ int      counts[PBLK];         // uncapped valid count
    __shared__ int      queue[PBLK * NS];     // compacted (p<<12 | idx)
    __shared__ unsigned pooled[PBLK][C2 + 1]; // stride 65: bank=(p+o)%32
    __shared__ float    ctr[PBLK][3];
    __shared__ float    dens[PBLK];
    __shared__ int      qtotal;

    const int tid   = threadIdx.x;
    const int lane  = tid & 63;
    const int wf    = tid >> 6;
    const int pt0   = blockIdx.x * PBLK;      // never straddles a batch
    const int b     = pt0 >> 12;
    const int bbase = b << 12;

    for (int u = tid; u < PBLK * (C2 + 1); u += 256) ((unsigned*)pooled)[u] = 0u;
    if (tid < PBLK) {
        ctr[tid][0] = xyz[(size_t)(pt0 + tid) * 3 + 0];
        ctr[tid][1] = xyz[(size_t)(pt0 + tid) * 3 + 1];
        ctr[tid][2] = xyz[(size_t)(pt0 + tid) * 3 + 2];
    }

    // ---- per-wave center constants: t = q·(-2c) + (|c|^2 - r^2 - band) ----
    const int c0 = pt0 + wf * CPW;
    float c2x[CPW], c2y[CPW], c2z[CPW], scc[CPW];
    #pragma unroll
    for (int j = 0; j < CPW; ++j) {           // uniform addr -> scalar loads
        const int g = __builtin_amdgcn_readfirstlane(c0 + j);
        const float cx = xyz[(size_t)g * 3 + 0];
        const float cy = xyz[(size_t)g * 3 + 1];
        const float cz = xyz[(size_t)g * 3 + 2];
        c2x[j] = -2.0f * cx;                  // exact (pow2 scale)
        c2y[j] = -2.0f * cy;
        c2z[j] = -2.0f * cz;
        scc[j] = fmaf(cx, cx, fmaf(cy, cy, cz * cz)) - (R2C + BAND);
    }
    int cnt[CPW];
    #pragma unroll
    for (int j = 0; j < CPW; ++j) cnt[j] = 0;

    // ---- Phase 1: scan. lane = candidate; one branch per tile ----
    const float* bx = SOA ? (sx + bbase) : nullptr;
    const float* by = SOA ? (sy + bbase) : nullptr;
    const float* bz = SOA ? (sz + bbase) : nullptr;
    const float* xb = xyz + (size_t)bbase * 3;

    float qx, qy, qz;
    if (SOA) { qx = bx[lane]; qy = by[lane]; qz = bz[lane]; }
    else     { qx = xb[lane*3+0]; qy = xb[lane*3+1]; qz = xb[lane*3+2]; }

    for (int m0 = 0; m0 < BQ_N; m0 += 64) {
        float nqx = 0.f, nqy = 0.f, nqz = 0.f;
        if (m0 + 64 < BQ_N) {                 // prefetch next tile (uniform)
            const int mn = m0 + 64 + lane;
            if (SOA) { nqx = bx[mn]; nqy = by[mn]; nqz = bz[mn]; }
            else     { nqx = xb[mn*3+0]; nqy = xb[mn*3+1]; nqz = xb[mn*3+2]; }
        }
        const float nsq = -fmaf(qx, qx, fmaf(qy, qy, qz * qz));  // -|q|^2

        float t[CPW];
        unsigned long long msk[CPW];
        #pragma unroll
        for (int j = 0; j < CPW; ++j) {       // unconditional: VALU only, good ILP
            t[j] = fmaf(qx, c2x[j], fmaf(qy, c2y[j], fmaf(qz, c2z[j], scc[j])));
            msk[j] = __ballot(t[j] < nsq);    // near: d2 < r2+band
        }
        if ((msk[0] | msk[1] | msk[2] | msk[3]) != 0ull) {   // ~30% of tiles
            #pragma unroll
            for (int j = 0; j < CPW; ++j) {
                unsigned long long mask = msk[j];
                if (mask == 0ull) continue;
                const float u = t[j] - nsq;                  // = d2 - r2 - band
                const bool nearb  = (mask >> lane) & 1ull;
                const bool strict = u < (-2.0f * BAND);      // d2 < r2-band
                bool valid = strict;
                const unsigned long long mS = __ballot(strict);
                if (mS != mask) {                            // borderline: exact fp64
                    if (nearb && !strict) {
                        const double cx = -0.5 * (double)c2x[j];
                        const double cy = -0.5 * (double)c2y[j];
                        const double cz = -0.5 * (double)c2z[j];
                        const double dx = (double)qx - cx;
                        const double dy = (double)qy - cy;
                        const double dz = (double)qz - cz;
                        valid = (dx * dx + dy * dy + dz * dz) < 0.0625;
                    }
                    mask = __ballot(valid);
                    if (mask == 0ull) continue;
                }
                const unsigned mlo = (unsigned)mask, mhi = (unsigned)(mask >> 32);
                const int rank = __builtin_amdgcn_mbcnt_hi(
                                     mhi, __builtin_amdgcn_mbcnt_lo(mlo, 0));
                const int pos = cnt[j] + rank;
                if (valid && pos < NS) lists[wf * CPW + j][pos] = m0 + lane;
                cnt[j] += __popcll(mask);
            }
        }
        qx = nqx; qy = nqy; qz = nqz;
    }
    if (lane == 0) {
        #pragma unroll
        for (int j = 0; j < CPW; ++j) counts[wf * CPW + j] = cnt[j];
    }
    __syncthreads();

    // ---- Phase 2: density + compact queue (first PBLK threads) ----
    if (tid < PBLK) {
        const int p = tid;
        const int ktot = counts[p];
        const int k = ktot < NS ? ktot : NS;   // == unique_cnt
        dens[p] = (float)k * (1.0f / (float)C2);

        int incl = k;
        #pragma unroll
        for (int d = 1; d < PBLK; d <<= 1) {
            int v = __shfl_up(incl, d, 64);
            if (lane >= d) incl += v;
        }
        const int excl = incl - k;
        if (p == PBLK - 1) qtotal = incl;

        for (int j = 0; j < k; ++j)
            queue[excl + j] = (p << 12) | lists[p][j];
    }
    __syncthreads();

    // ---- Phase 3: MLP on distinct samples ----
    const int Q = qtotal;
    for (int j = tid; j < Q; j += 256) {
        const int e   = queue[j];
        const int p   = e >> 12;
        const int idx = e & (BQ_N - 1);
        const float* nb = xyz + (size_t)(bbase + idx) * 3;
        const float rx = nb[0] - ctr[p][0];
        const float ry = nb[1] - ctr[p][1];
        const float rz = nb[2] - ctr[p][2];

        float h1[C1];
        #pragma unroll
        for (int c = 0; c < C1; ++c) {          // w1/b1 uniform -> scalar loads
            float a = fmaf(w1[c * 3 + 2], rz,
                      fmaf(w1[c * 3 + 1], ry,
                      fmaf(w1[c * 3 + 0], rx, b1[c])));
            h1[c] = a > 0.0f ? a : 0.0f;
        }
        #pragma unroll 2
        for (int o = 0; o < C2; ++o) {          // w2 uniform -> scalar loads
            float acc = b2[o];
            #pragma unroll
            for (int i = 0; i < C1; ++i) acc = fmaf(w2[o * C1 + i], h1[i], acc);
            acc = acc > 0.0f ? acc : 0.0f;
            atomicMax(&pooled[p][o], __float_as_uint(acc));
        }
    }
    __syncthreads();

    // ---- Phase 4: write out (B, N, 65) ----
    for (int u = tid; u < PBLK * (C2 + 1); u += 256) {
        const int p = u / (C2 + 1);
        const int c = u % (C2 + 1);
        const float v = (c < C2) ? __uint_as_float(pooled[p][c]) : dens[p];
        out[(size_t)(pt0 + p) * (C2 + 1) + c] = v;
    }
}

extern "C" void kernel_launch(void* const* d_in, const int* in_sizes, int n_in,
                              void* d_out, int out_size, void* d_ws, size_t ws_size,
                              hipStream_t stream) {
    const float* xyz = (const float*)d_in[0];
    const float* w1  = (const float*)d_in[1];
    const float* b1  = (const float*)d_in[2];
    const float* w2  = (const float*)d_in[3];
    const float* b2  = (const float*)d_in[4];
    float* out = (float*)d_out;

    const int nblocks = NPTS / PBLK;          // 2048
    const size_t soa_need = (size_t)3 * NPTS * sizeof(float);  // 393216 B

    if (ws_size >= soa_need) {
        float* sx = (float*)d_ws;
        float* sy = sx + NPTS;
        float* sz = sy + NPTS;
        soa_kernel<<<(NPTS + 255) / 256, 256, 0, stream>>>(xyz, sx, sy, sz);
        lse_kernel<true><<<nblocks, 256, 0, stream>>>(xyz, sx, sy, sz,
                                                      w1, b1, w2, b2, out);
    } else {
        lse_kernel<false><<<nblocks, 256, 0, stream>>>(xyz, nullptr, nullptr, nullptr,
                                                       w1, b1, w2, b2, out);
    }
}